// Round 4
// baseline (724.964 us; speedup 1.0000x reference)
//
#include <hip/hip_runtime.h>
#include <hip/hip_bf16.h>
#include <cstdint>

typedef __attribute__((ext_vector_type(8))) short short8;
typedef __attribute__((ext_vector_type(4))) short short4_t;
typedef __attribute__((ext_vector_type(4))) float f32x4;

#define MFMA16(a, b, c) __builtin_amdgcn_mfma_f32_16x16x32_bf16(a, b, c, 0, 0, 0)

__device__ __forceinline__ short f2b(float f) {
    union { float fp; unsigned u; } un; un.fp = f;
    unsigned r = un.u + 0x7fffu + ((un.u >> 16) & 1u);
    return (short)(r >> 16);
}

#if __has_builtin(__builtin_amdgcn_cvt_pk_bf16_f32)
__device__ __forceinline__ unsigned pk_bf16(float a, float b) {
    auto r = __builtin_amdgcn_cvt_pk_bf16_f32(a, b);
    unsigned u; __builtin_memcpy(&u, &r, 4); return u;
}
#else
__device__ __forceinline__ unsigned pk_bf16(float a, float b) {
    return (unsigned)(unsigned short)f2b(a) | ((unsigned)(unsigned short)f2b(b) << 16);
}
#endif

typedef const __attribute__((address_space(1))) unsigned g_as1;
typedef __attribute__((address_space(3))) unsigned l_as3;
__device__ __forceinline__ void gll16(const ushort* g, ushort* l) {
    __builtin_amdgcn_global_load_lds((g_as1*)g, (l_as3*)l, 16, 0, 0);
}

// ---------------------------------------------------------------------------
// fp32 -> bf16 convert of query / context
// ---------------------------------------------------------------------------
__global__ __launch_bounds__(256) void in_cvt_kernel(
    const float* __restrict__ q, const float* __restrict__ c,
    ushort* __restrict__ qb, ushort* __restrict__ cb)
{
    const float* src = blockIdx.y ? c : q;
    ushort* dst = blockIdx.y ? cb : qb;
    size_t i = ((size_t)blockIdx.x * 256 + threadIdx.x) * 8;
    float4 v0 = *(const float4*)&src[i];
    float4 v1 = *(const float4*)&src[i + 4];
    uint4 o;
    o.x = pk_bf16(v0.x, v0.y); o.y = pk_bf16(v0.z, v0.w);
    o.z = pk_bf16(v1.x, v1.y); o.w = pk_bf16(v1.z, v1.w);
    *(uint4*)&dst[i] = o;
}

// ---------------------------------------------------------------------------
// Weight transpose+convert: fp32 [k][n] -> bf16 [n][k]
// ---------------------------------------------------------------------------
__global__ __launch_bounds__(256) void wt_cvt_kernel(
    const float* __restrict__ Wq, const float* __restrict__ Wk,
    const float* __restrict__ Wv, const float* __restrict__ Wo,
    ushort* __restrict__ wt)
{
    __shared__ float Ts[64 * 65];
    const int z = blockIdx.z;
    const float* W = (z == 0) ? Wq : (z == 1) ? Wk : (z == 2) ? Wv : Wo;
    ushort* WT = wt + (size_t)z * (1024 * 1024);
    const int n0 = blockIdx.x * 64, k0 = blockIdx.y * 64;
    const int tid = threadIdx.x;

#pragma unroll
    for (int rr = 0; rr < 4; ++rr) {
        int u = tid + rr * 256;
        int r = u >> 4, c = (u & 15) * 4;
        float4 v = *(const float4*)&W[(size_t)(k0 + r) * 1024 + n0 + c];
        Ts[r * 65 + c + 0] = v.x; Ts[r * 65 + c + 1] = v.y;
        Ts[r * 65 + c + 2] = v.z; Ts[r * 65 + c + 3] = v.w;
    }
    __syncthreads();
#pragma unroll
    for (int rr = 0; rr < 4; ++rr) {
        int u = tid + rr * 256;
        int rn = u >> 4, ck = (u & 15) * 4;
        short4_t o;
        o[0] = f2b(Ts[(ck + 0) * 65 + rn]);
        o[1] = f2b(Ts[(ck + 1) * 65 + rn]);
        o[2] = f2b(Ts[(ck + 2) * 65 + rn]);
        o[3] = f2b(Ts[(ck + 3) * 65 + rn]);
        *(short4_t*)&WT[(size_t)(n0 + rn) * 1024 + k0 + ck] = o;
    }
}

// ---------------------------------------------------------------------------
// Fused QKV projection, 1536 blocks (1D), 8x8 block-group swizzle:
//   gid>>6 -> group (gx = z in 0..2, gy = m-supertile); gid&63 -> 8n x 8m.
//   Same-XCD slice (gid mod 8 fixed) pins one n-tile -> weight panel reused
//   8x inside its XCD L2.
// Epilogue: acc -> LDS staging (34 KB, reuses As/Bs) -> cooperative uint4
// stores: every store instruction covers contiguous full lines (the R3
// kernel's 8B scattered stores caused 28x write amplification under L2
// thrash -> partial-line evictions + RMW).
// ---------------------------------------------------------------------------
__global__ __launch_bounds__(256, 4) void qkv_kernel(
    const ushort* __restrict__ Qb, const ushort* __restrict__ Cb,
    const ushort* __restrict__ WT,
    const float* __restrict__ bq, const float* __restrict__ bk,
    const float* __restrict__ bv,
    ushort* __restrict__ Qw, ushort* __restrict__ Kw, ushort* __restrict__ Vtw,
    float qscale)
{
    __shared__ ushort smem_u[17408];            // 34816 B: As(8K) + Bs(8K) / stage
    ushort* As = smem_u;
    ushort* Bs = smem_u + 8192;

    const int tid = threadIdx.x;
    const int w = tid >> 6, lane = tid & 63;
    const int ln = tid & 15, quad = (tid >> 4) & 3;
    const int wm = w >> 1, wn = w & 1;

    const int gid = blockIdx.x;
    const int g = gid >> 6, r8 = gid & 63;
    const int z = g % 3, gy = g / 3;
    const int n0l = (r8 & 7) * 128;
    const int m0 = (gy * 8 + (r8 >> 3)) * 128;

    const ushort* Ag = (z == 0) ? Qb : Cb;
    const ushort* Bz = WT + (size_t)z * 1048576;

    int offA[4], offB[4], lseg[4];
#pragma unroll
    for (int rr = 0; rr < 4; ++rr) {
        int idx = (rr * 4 + w) * 64 + lane;
        int rr2 = idx >> 3, cst = idx & 7, csrc = cst ^ (rr2 & 7);
        offA[rr] = (m0 + rr2) * 1024 + csrc * 8;
        offB[rr] = (n0l + rr2) * 1024 + csrc * 8;
        lseg[rr] = (rr * 4 + w) * 512;
    }

    f32x4 acc[4][4] = {};

    for (int kk = 0; kk < 1024; kk += 64) {
        __syncthreads();
#pragma unroll
        for (int rr = 0; rr < 4; ++rr)
            gll16(&Ag[(size_t)(offA[rr] + kk)], &As[lseg[rr]]);
#pragma unroll
        for (int rr = 0; rr < 4; ++rr)
            gll16(&Bz[(size_t)(offB[rr] + kk)], &Bs[lseg[rr]]);
        __syncthreads();

#pragma unroll
        for (int ks = 0; ks < 2; ++ks) {
            short8 af[4], bfr[4];
#pragma unroll
            for (int i = 0; i < 4; ++i)
                af[i] = *(const short8*)&As[(wm * 64 + i * 16 + ln) * 64 +
                                            ((ks * 4 + quad) ^ (ln & 7)) * 8];
#pragma unroll
            for (int j = 0; j < 4; ++j)
                bfr[j] = *(const short8*)&Bs[(wn * 64 + j * 16 + ln) * 64 +
                                             ((ks * 4 + quad) ^ (ln & 7)) * 8];
            if (z == 2) {
#pragma unroll
                for (int i = 0; i < 4; ++i)
#pragma unroll
                    for (int j = 0; j < 4; ++j)
                        acc[i][j] = MFMA16(af[i], bfr[j], acc[i][j]);
            } else {
#pragma unroll
                for (int i = 0; i < 4; ++i)
#pragma unroll
                    for (int j = 0; j < 4; ++j)
                        acc[i][j] = MFMA16(bfr[j], af[i], acc[i][j]);
            }
        }
    }

    __syncthreads();                            // all waves done with As/Bs
    const int b = m0 >> 11;                     // batch (m-tile within one b)

    if (z != 2) {
        // swapped acc: col(ln) = t-local, quad*4+reg = n-local
        ushort* Out = (z == 0) ? Qw : Kw;
        const float* bias = (z == 0) ? bq : bk;
        float scl = (z == 0) ? qscale : 1.0f;
#pragma unroll
        for (int j = 0; j < 4; ++j) {
            int nloc = wn * 64 + j * 16 + quad * 4;
            f32x4 b4 = *(const f32x4*)&bias[n0l + nloc];
#pragma unroll
            for (int i = 0; i < 4; ++i) {
                int t = wm * 64 + i * 16 + ln;
                uint2 o;
                o.x = pk_bf16((acc[i][j][0] + b4[0]) * scl, (acc[i][j][1] + b4[1]) * scl);
                o.y = pk_bf16((acc[i][j][2] + b4[2]) * scl, (acc[i][j][3] + b4[3]) * scl);
                *(uint2*)&smem_u[t * 136 + nloc] = o;    // stage [t][n]
            }
        }
        __syncthreads();
#pragma unroll
        for (int it = 0; it < 8; ++it) {
            int e = it * 2048 + tid * 8;
            int t = e >> 7, n = e & 127;
            uint4 v = *(const uint4*)&smem_u[t * 136 + n];
            int h = (n0l + n) >> 6, d = n & 63;
            int tt = (m0 + t) & 2047;
            *(uint4*)&Out[(((size_t)(b * 16 + h) * 2048 + tt) << 6) + d] = v;
        }
    } else {
        // unswapped acc: col(ln) = n-local, quad*4+reg = t-local
#pragma unroll
        for (int j = 0; j < 4; ++j) {
            int nloc = wn * 64 + j * 16 + ln;
            float bvv = bv[n0l + nloc];
#pragma unroll
            for (int i = 0; i < 4; ++i) {
                int tloc = wm * 64 + i * 16 + quad * 4;
                uint2 o;
                o.x = pk_bf16(acc[i][j][0] + bvv, acc[i][j][1] + bvv);
                o.y = pk_bf16(acc[i][j][2] + bvv, acc[i][j][3] + bvv);
                *(uint2*)&smem_u[nloc * 136 + tloc] = o;  // stage [n][t]
            }
        }
        __syncthreads();
#pragma unroll
        for (int it = 0; it < 8; ++it) {
            int e = it * 2048 + tid * 8;
            int n = e >> 7, t = e & 127;
            uint4 v = *(const uint4*)&smem_u[n * 136 + t];
            int h = (n0l + n) >> 6, d = n & 63;
            int tt = (m0 + t) & 2047;
            *(uint4*)&Vtw[(((size_t)((b * 16 + h) * 64 + d)) << 11) + tt] = v;
        }
    }
}

// ---------------------------------------------------------------------------
// Output projection: fp32 out [t][1024]. Unswapped acc -> per-reg scalar f32
// stores give 4 x 64B full-sector runs per instruction. 8x8 block swizzle.
// ---------------------------------------------------------------------------
__global__ __launch_bounds__(256, 4) void gemm_o_kernel(
    const ushort* __restrict__ Ag, const ushort* __restrict__ BT,
    const float* __restrict__ bias, float* __restrict__ Out)
{
    __shared__ ushort As[128 * 64];
    __shared__ ushort Bs[128 * 64];
    const int tid = threadIdx.x;
    const int w = tid >> 6, lane = tid & 63;
    const int ln = tid & 15, quad = (tid >> 4) & 3;
    const int wm = w >> 1, wn = w & 1;

    const int gid = blockIdx.x;
    const int g = gid >> 6, r8 = gid & 63;
    const int n0 = (r8 & 7) * 128;
    const int m0 = (g * 8 + (r8 >> 3)) * 128;

    int offA[4], offB[4], lseg[4];
#pragma unroll
    for (int rr = 0; rr < 4; ++rr) {
        int idx = (rr * 4 + w) * 64 + lane;
        int rr2 = idx >> 3, cst = idx & 7, csrc = cst ^ (rr2 & 7);
        offA[rr] = (m0 + rr2) * 1024 + csrc * 8;
        offB[rr] = (n0 + rr2) * 1024 + csrc * 8;
        lseg[rr] = (rr * 4 + w) * 512;
    }

    f32x4 acc[4][4] = {};

    for (int kk = 0; kk < 1024; kk += 64) {
        __syncthreads();
#pragma unroll
        for (int rr = 0; rr < 4; ++rr)
            gll16(&Ag[(size_t)(offA[rr] + kk)], &As[lseg[rr]]);
#pragma unroll
        for (int rr = 0; rr < 4; ++rr)
            gll16(&BT[(size_t)(offB[rr] + kk)], &Bs[lseg[rr]]);
        __syncthreads();

#pragma unroll
        for (int ks = 0; ks < 2; ++ks) {
            short8 af[4], bfr[4];
#pragma unroll
            for (int i = 0; i < 4; ++i)
                af[i] = *(const short8*)&As[(wm * 64 + i * 16 + ln) * 64 +
                                            ((ks * 4 + quad) ^ (ln & 7)) * 8];
#pragma unroll
            for (int j = 0; j < 4; ++j)
                bfr[j] = *(const short8*)&Bs[(wn * 64 + j * 16 + ln) * 64 +
                                             ((ks * 4 + quad) ^ (ln & 7)) * 8];
#pragma unroll
            for (int i = 0; i < 4; ++i)
#pragma unroll
                for (int j = 0; j < 4; ++j)
                    acc[i][j] = MFMA16(af[i], bfr[j], acc[i][j]);
        }
    }

#pragma unroll
    for (int j = 0; j < 4; ++j) {
        int n = n0 + wn * 64 + j * 16 + ln;
        float bvv = bias[n];
#pragma unroll
        for (int i = 0; i < 4; ++i) {
            int mb = m0 + wm * 64 + i * 16 + quad * 4;
#pragma unroll
            for (int r = 0; r < 4; ++r)
                Out[(size_t)(mb + r) * 1024 + n] = acc[i][j][r] + bvv;
        }
    }
}

// ---------------------------------------------------------------------------
// Flash attention (unchanged from R3): fixed-max softmax, double-buffered
// K/V prefetch, swapped PV -> per-lane 1/l, b64 stores.
// ---------------------------------------------------------------------------
__global__ __launch_bounds__(256, 3) void attn_kernel(
    const ushort* __restrict__ Qw, const ushort* __restrict__ Kw,
    const ushort* __restrict__ Vtw, ushort* __restrict__ attn)
{
    __shared__ ushort Ks[2][64 * 64];
    __shared__ ushort Vts[2][64 * 64];
    __shared__ ushort Ps[128 * 64];

    const int tid = threadIdx.x;
    const int w = tid >> 6, lane = tid & 63;
    const int ln = tid & 15, quad = (tid >> 4) & 3;
    const int bh = blockIdx.x, b = bh >> 4, h = bh & 15;
    const int qt = blockIdx.y;

    const ushort* Qg = Qw + (size_t)bh * 131072 + (size_t)qt * 8192;
    const ushort* Kg = Kw + (size_t)bh * 131072;
    const ushort* Vg = Vtw + (size_t)bh * 131072;

    short8 bq[2][2];
#pragma unroll
    for (int qs = 0; qs < 2; ++qs)
#pragma unroll
        for (int ks = 0; ks < 2; ++ks)
            bq[qs][ks] = *(const short8*)&Qg[(w * 32 + qs * 16 + ln) * 64 + ks * 32 + quad * 8];

    int offK[2], offV[2], lseg[2];
#pragma unroll
    for (int rr = 0; rr < 2; ++rr) {
        int idx = (rr * 4 + w) * 64 + lane;
        int r = idx >> 3, cst = idx & 7, csrc = cst ^ (r & 7);
        offK[rr] = r * 64 + csrc * 8;
        offV[rr] = r * 2048 + csrc * 8;
        lseg[rr] = (rr * 4 + w) * 512;
    }

#pragma unroll
    for (int rr = 0; rr < 2; ++rr) gll16(&Kg[offK[rr]], &Ks[0][lseg[rr]]);
#pragma unroll
    for (int rr = 0; rr < 2; ++rr) gll16(&Vg[offV[rr]], &Vts[0][lseg[rr]]);

    f32x4 Of[2][4] = {};
    float psum[2] = {0.f, 0.f};

    for (int kt = 0; kt < 32; ++kt) {
        __syncthreads();
        const int cur = kt & 1;
        if (kt < 31) {
            const int nx = cur ^ 1;
#pragma unroll
            for (int rr = 0; rr < 2; ++rr)
                gll16(&Kg[(kt + 1) * 4096 + offK[rr]], &Ks[nx][lseg[rr]]);
#pragma unroll
            for (int rr = 0; rr < 2; ++rr)
                gll16(&Vg[(kt + 1) * 64 + offV[rr]], &Vts[nx][lseg[rr]]);
        }
        const ushort* ksm = Ks[cur];
        const ushort* vsm = Vts[cur];

        f32x4 sa[4][2];
#pragma unroll
        for (int kv = 0; kv < 4; ++kv) {
            short8 a0 = *(const short8*)&ksm[(kv * 16 + ln) * 64 + (quad ^ (ln & 7)) * 8];
            short8 a1 = *(const short8*)&ksm[(kv * 16 + ln) * 64 + ((4 + quad) ^ (ln & 7)) * 8];
#pragma unroll
            for (int qs = 0; qs < 2; ++qs) {
                f32x4 s = {};
                s = MFMA16(a0, bq[qs][0], s);
                s = MFMA16(a1, bq[qs][1], s);
                sa[kv][qs] = s;
            }
        }

#pragma unroll
        for (int qs = 0; qs < 2; ++qs) {
            int qrow = w * 32 + qs * 16 + ln;
#pragma unroll
            for (int kv = 0; kv < 4; ++kv) {
                float p0 = __builtin_amdgcn_exp2f(sa[kv][qs][0]);
                float p1 = __builtin_amdgcn_exp2f(sa[kv][qs][1]);
                float p2 = __builtin_amdgcn_exp2f(sa[kv][qs][2]);
                float p3 = __builtin_amdgcn_exp2f(sa[kv][qs][3]);
                psum[qs] += (p0 + p1) + (p2 + p3);
                uint2 pk2;
                pk2.x = pk_bf16(p0, p1);
                pk2.y = pk_bf16(p2, p3);
                int c = 2 * kv + (quad >> 1);
                *(uint2*)&Ps[qrow * 64 + ((c ^ (ln & 7)) * 8) + (quad & 1) * 4] = pk2;
            }
        }

#pragma unroll
        for (int ks = 0; ks < 2; ++ks) {
            short8 vb[4], pa[2];
#pragma unroll
            for (int ds = 0; ds < 4; ++ds)
                vb[ds] = *(const short8*)&vsm[(ds * 16 + ln) * 64 +
                                              ((ks * 4 + quad) ^ (ln & 7)) * 8];
#pragma unroll
            for (int qs = 0; qs < 2; ++qs)
                pa[qs] = *(const short8*)&Ps[(w * 32 + qs * 16 + ln) * 64 +
                                             ((ks * 4 + quad) ^ (ln & 7)) * 8];
#pragma unroll
            for (int qs = 0; qs < 2; ++qs)
#pragma unroll
                for (int ds = 0; ds < 4; ++ds)
                    Of[qs][ds] = MFMA16(vb[ds], pa[qs], Of[qs][ds]);
        }
    }

#pragma unroll
    for (int qs = 0; qs < 2; ++qs) {
        float l = psum[qs];
        l += __shfl_xor(l, 16);
        l += __shfl_xor(l, 32);
        float inv = __builtin_amdgcn_rcpf(l);
        int t = qt * 128 + w * 32 + qs * 16 + ln;
        size_t base = ((size_t)(b * 2048 + t) << 10) + h * 64;
#pragma unroll
        for (int ds = 0; ds < 4; ++ds) {
            uint2 o;
            o.x = pk_bf16(Of[qs][ds][0] * inv, Of[qs][ds][1] * inv);
            o.y = pk_bf16(Of[qs][ds][2] * inv, Of[qs][ds][3] * inv);
            *(uint2*)&attn[base + ds * 16 + quad * 4] = o;
        }
    }
}

// ---------------------------------------------------------------------------
extern "C" void kernel_launch(void* const* d_in, const int* in_sizes, int n_in,
                              void* d_out, int out_size, void* d_ws, size_t ws_size,
                              hipStream_t stream)
{
    const float* query   = (const float*)d_in[0];
    const float* context = (const float*)d_in[1];
    const float* Wq = (const float*)d_in[2];
    const float* bq = (const float*)d_in[3];
    const float* Wk = (const float*)d_in[4];
    const float* bk = (const float*)d_in[5];
    const float* Wv = (const float*)d_in[6];
    const float* bv = (const float*)d_in[7];
    const float* Wo = (const float*)d_in[8];
    const float* bo = (const float*)d_in[9];

    char* ws = (char*)d_ws;
    ushort* WT  = (ushort*)ws;                        // 4 x 2 MB bf16 [n][k]
    ushort* Qb  = (ushort*)(ws + 8388608);            // query bf16; later Aw
    ushort* Qw  = (ushort*)(ws + 25165824);           // [b,h,t,d] (pre-scaled)
    ushort* Kw  = (ushort*)(ws + 41943040);           // [b,h,t,d]
    ushort* Vtw = (ushort*)(ws + 58720256);           // [b,h,d,t]
    ushort* Aw  = Qb;                                 // attn out reuses Qb
    ushort* Cb  = (ushort*)d_out;                     // context bf16 in d_out

    const float SCALE = 0.18033688011112042f;         // log2(e)/sqrt(64)

    in_cvt_kernel<<<dim3(4096, 2), 256, 0, stream>>>(query, context, Qb, Cb);
    wt_cvt_kernel<<<dim3(16, 16, 4), 256, 0, stream>>>(Wq, Wk, Wv, Wo, WT);
    qkv_kernel<<<dim3(1536), 256, 0, stream>>>(Qb, Cb, WT, bq, bk, bv,
                                               Qw, Kw, Vtw, SCALE);
    attn_kernel<<<dim3(64, 16), 256, 0, stream>>>(Qw, Kw, Vtw, Aw);
    gemm_o_kernel<<<dim3(512), 256, 0, stream>>>(Aw, WT + 3 * 1048576, bo,
                                                 (float*)d_out);
}

// Round 5
// 329.271 us; speedup vs baseline: 2.2017x; 2.2017x over previous
//
#include <hip/hip_runtime.h>
#include <hip/hip_bf16.h>
#include <cstdint>

typedef __attribute__((ext_vector_type(8))) short short8;
typedef __attribute__((ext_vector_type(4))) short short4_t;
typedef __attribute__((ext_vector_type(4))) float f32x4;

#define MFMA16(a, b, c) __builtin_amdgcn_mfma_f32_16x16x32_bf16(a, b, c, 0, 0, 0)

__device__ __forceinline__ short f2b(float f) {
    union { float fp; unsigned u; } un; un.fp = f;
    unsigned r = un.u + 0x7fffu + ((un.u >> 16) & 1u);
    return (short)(r >> 16);
}

#if __has_builtin(__builtin_amdgcn_cvt_pk_bf16_f32)
__device__ __forceinline__ unsigned pk_bf16(float a, float b) {
    auto r = __builtin_amdgcn_cvt_pk_bf16_f32(a, b);
    unsigned u; __builtin_memcpy(&u, &r, 4); return u;
}
#else
__device__ __forceinline__ unsigned pk_bf16(float a, float b) {
    return (unsigned)(unsigned short)f2b(a) | ((unsigned)(unsigned short)f2b(b) << 16);
}
#endif

typedef const __attribute__((address_space(1))) unsigned g_as1;
typedef __attribute__((address_space(3))) unsigned l_as3;
__device__ __forceinline__ void gll16(const ushort* g, ushort* l) {
    __builtin_amdgcn_global_load_lds((g_as1*)g, (l_as3*)l, 16, 0, 0);
}

// ---------------------------------------------------------------------------
// fp32 -> bf16 convert of query / context
// ---------------------------------------------------------------------------
__global__ __launch_bounds__(256) void in_cvt_kernel(
    const float* __restrict__ q, const float* __restrict__ c,
    ushort* __restrict__ qb, ushort* __restrict__ cb)
{
    const float* src = blockIdx.y ? c : q;
    ushort* dst = blockIdx.y ? cb : qb;
    size_t i = ((size_t)blockIdx.x * 256 + threadIdx.x) * 8;
    float4 v0 = *(const float4*)&src[i];
    float4 v1 = *(const float4*)&src[i + 4];
    uint4 o;
    o.x = pk_bf16(v0.x, v0.y); o.y = pk_bf16(v0.z, v0.w);
    o.z = pk_bf16(v1.x, v1.y); o.w = pk_bf16(v1.z, v1.w);
    *(uint4*)&dst[i] = o;
}

// ---------------------------------------------------------------------------
// Weight transpose+convert: fp32 [k][n] -> bf16 [n][k]
// ---------------------------------------------------------------------------
__global__ __launch_bounds__(256) void wt_cvt_kernel(
    const float* __restrict__ Wq, const float* __restrict__ Wk,
    const float* __restrict__ Wv, const float* __restrict__ Wo,
    ushort* __restrict__ wt)
{
    __shared__ float Ts[64 * 65];
    const int z = blockIdx.z;
    const float* W = (z == 0) ? Wq : (z == 1) ? Wk : (z == 2) ? Wv : Wo;
    ushort* WT = wt + (size_t)z * (1024 * 1024);
    const int n0 = blockIdx.x * 64, k0 = blockIdx.y * 64;
    const int tid = threadIdx.x;

#pragma unroll
    for (int rr = 0; rr < 4; ++rr) {
        int u = tid + rr * 256;
        int r = u >> 4, c = (u & 15) * 4;
        float4 v = *(const float4*)&W[(size_t)(k0 + r) * 1024 + n0 + c];
        Ts[r * 65 + c + 0] = v.x; Ts[r * 65 + c + 1] = v.y;
        Ts[r * 65 + c + 2] = v.z; Ts[r * 65 + c + 3] = v.w;
    }
    __syncthreads();
#pragma unroll
    for (int rr = 0; rr < 4; ++rr) {
        int u = tid + rr * 256;
        int rn = u >> 4, ck = (u & 15) * 4;
        short4_t o;
        o[0] = f2b(Ts[(ck + 0) * 65 + rn]);
        o[1] = f2b(Ts[(ck + 1) * 65 + rn]);
        o[2] = f2b(Ts[(ck + 2) * 65 + rn]);
        o[3] = f2b(Ts[(ck + 3) * 65 + rn]);
        *(short4_t*)&WT[(size_t)(n0 + rn) * 1024 + k0 + ck] = o;
    }
}

// ---------------------------------------------------------------------------
// GEMM (R2-proven structure): grid (8 n-tiles, 64 m-tiles), x-fastest ->
// consecutive blocks share the A panel; whole 2 MB weight stays L2-hot.
// MODE 0: out bf16 [b,h,t,d] scaled  (Q projection)
// MODE 3: out fp32 row-major [m][n]  (output projection)
// ---------------------------------------------------------------------------
template <int MODE>
__global__ __launch_bounds__(256) void gemm_kernel(
    const ushort* __restrict__ Ag, const ushort* __restrict__ BT,
    const float* __restrict__ bias, void* __restrict__ Outp, float scale)
{
    __shared__ ushort As[128 * 64];
    __shared__ ushort Bs[128 * 64];
    const int tid = threadIdx.x;
    const int w = tid >> 6, lane = tid & 63;
    const int ln = tid & 15, quad = (tid >> 4) & 3;
    const int wm = w >> 1, wn = w & 1;
    const int m0 = blockIdx.y * 128, n0 = blockIdx.x * 128;

    int offA[4], offB[4], lseg[4];
#pragma unroll
    for (int rr = 0; rr < 4; ++rr) {
        int idx = (rr * 4 + w) * 64 + lane;
        int r = idx >> 3, cst = idx & 7, csrc = cst ^ (r & 7);
        offA[rr] = (m0 + r) * 1024 + csrc * 8;
        offB[rr] = (n0 + r) * 1024 + csrc * 8;
        lseg[rr] = (rr * 4 + w) * 512;
    }

    f32x4 acc[4][4] = {};

    for (int kk = 0; kk < 1024; kk += 64) {
        __syncthreads();
#pragma unroll
        for (int rr = 0; rr < 4; ++rr)
            gll16(&Ag[(size_t)(offA[rr] + kk)], &As[lseg[rr]]);
#pragma unroll
        for (int rr = 0; rr < 4; ++rr)
            gll16(&BT[(size_t)(offB[rr] + kk)], &Bs[lseg[rr]]);
        __syncthreads();

#pragma unroll
        for (int ks = 0; ks < 2; ++ks) {
            short8 af[4], bfr[4];
#pragma unroll
            for (int i = 0; i < 4; ++i)
                af[i] = *(const short8*)&As[(wm * 64 + i * 16 + ln) * 64 +
                                            ((ks * 4 + quad) ^ (ln & 7)) * 8];
#pragma unroll
            for (int j = 0; j < 4; ++j)
                bfr[j] = *(const short8*)&Bs[(wn * 64 + j * 16 + ln) * 64 +
                                             ((ks * 4 + quad) ^ (ln & 7)) * 8];
#pragma unroll
            for (int i = 0; i < 4; ++i)
#pragma unroll
                for (int j = 0; j < 4; ++j)
                    acc[i][j] = MFMA16(af[i], bfr[j], acc[i][j]);
        }
    }

#pragma unroll
    for (int j = 0; j < 4; ++j) {
        int n = n0 + wn * 64 + j * 16 + ln;
        float bv = bias[n];
#pragma unroll
        for (int i = 0; i < 4; ++i) {
            int mb = m0 + wm * 64 + i * 16 + quad * 4;
            if (MODE == 3) {
                float* Out = (float*)Outp;
#pragma unroll
                for (int r = 0; r < 4; ++r)
                    Out[(size_t)(mb + r) * 1024 + n] = acc[i][j][r] + bv;
            } else {
                ushort* Out = (ushort*)Outp;
                int h = n >> 6, d = n & 63;
#pragma unroll
                for (int r = 0; r < 4; ++r) {
                    int m = mb + r, b = m >> 11, t = m & 2047;
                    Out[(((size_t)(b * 16 + h) * 2048 + t) << 6) + d] =
                        (ushort)f2b((acc[i][j][r] + bv) * scale);
                }
            }
        }
    }
}

// ---------------------------------------------------------------------------
// Fused K+V projection. grid (16, 64), x-fastest: x<8 -> K n-tile x, x>=8 ->
// V n-tile x-8. 16 consecutive blocks share one A (context) panel -> A fetch
// halves vs two dispatches; K+V weights = 4 MB working set. Epilogues are
// R2's proven MODE0 (K) / MODE2 (V).
// ---------------------------------------------------------------------------
__global__ __launch_bounds__(256) void kv_kernel(
    const ushort* __restrict__ Cb, const ushort* __restrict__ WTk,
    const ushort* __restrict__ WTv,
    const float* __restrict__ bk, const float* __restrict__ bv,
    ushort* __restrict__ Kw, ushort* __restrict__ Vtw)
{
    __shared__ ushort As[128 * 64];
    __shared__ ushort Bs[128 * 64];
    const int tid = threadIdx.x;
    const int w = tid >> 6, lane = tid & 63;
    const int ln = tid & 15, quad = (tid >> 4) & 3;
    const int wm = w >> 1, wn = w & 1;
    const int z = blockIdx.x >> 3;
    const int n0 = (blockIdx.x & 7) * 128;
    const int m0 = blockIdx.y * 128;
    const ushort* BT = z ? WTv : WTk;

    int offA[4], offB[4], lseg[4];
#pragma unroll
    for (int rr = 0; rr < 4; ++rr) {
        int idx = (rr * 4 + w) * 64 + lane;
        int r = idx >> 3, cst = idx & 7, csrc = cst ^ (r & 7);
        offA[rr] = (m0 + r) * 1024 + csrc * 8;
        offB[rr] = (n0 + r) * 1024 + csrc * 8;
        lseg[rr] = (rr * 4 + w) * 512;
    }

    f32x4 acc[4][4] = {};

    for (int kk = 0; kk < 1024; kk += 64) {
        __syncthreads();
#pragma unroll
        for (int rr = 0; rr < 4; ++rr)
            gll16(&Cb[(size_t)(offA[rr] + kk)], &As[lseg[rr]]);
#pragma unroll
        for (int rr = 0; rr < 4; ++rr)
            gll16(&BT[(size_t)(offB[rr] + kk)], &Bs[lseg[rr]]);
        __syncthreads();

#pragma unroll
        for (int ks = 0; ks < 2; ++ks) {
            short8 af[4], bfr[4];
#pragma unroll
            for (int i = 0; i < 4; ++i)
                af[i] = *(const short8*)&As[(wm * 64 + i * 16 + ln) * 64 +
                                            ((ks * 4 + quad) ^ (ln & 7)) * 8];
#pragma unroll
            for (int j = 0; j < 4; ++j)
                bfr[j] = *(const short8*)&Bs[(wn * 64 + j * 16 + ln) * 64 +
                                             ((ks * 4 + quad) ^ (ln & 7)) * 8];
#pragma unroll
            for (int i = 0; i < 4; ++i)
#pragma unroll
                for (int j = 0; j < 4; ++j)
                    acc[i][j] = MFMA16(af[i], bfr[j], acc[i][j]);
        }
    }

#pragma unroll
    for (int j = 0; j < 4; ++j) {
        int n = n0 + wn * 64 + j * 16 + ln;
        int h = n >> 6, d = n & 63;
        if (z == 0) {
            float bvv = bk[n];
#pragma unroll
            for (int i = 0; i < 4; ++i) {
                int mb = m0 + wm * 64 + i * 16 + quad * 4;
#pragma unroll
                for (int r = 0; r < 4; ++r) {
                    int m = mb + r, b = m >> 11, t = m & 2047;
                    Kw[(((size_t)(b * 16 + h) * 2048 + t) << 6) + d] =
                        (ushort)f2b(acc[i][j][r] + bvv);
                }
            }
        } else {
            float bvv = bv[n];
#pragma unroll
            for (int i = 0; i < 4; ++i) {
                int mb = m0 + wm * 64 + i * 16 + quad * 4;
                int b = mb >> 11, t = mb & 2047;
                short4_t o;
                o[0] = f2b(acc[i][j][0] + bvv); o[1] = f2b(acc[i][j][1] + bvv);
                o[2] = f2b(acc[i][j][2] + bvv); o[3] = f2b(acc[i][j][3] + bvv);
                *(short4_t*)&Vtw[(((size_t)((b * 16 + h) * 64 + d)) << 11) + t] = o;
            }
        }
    }
}

// ---------------------------------------------------------------------------
// Flash attention = R2's kernel + single-barrier double-buffered K/V
// prefetch (only change). Fixed-max softmax (Q pre-scaled by log2e/8),
// per-wave-private P rows (no P barrier needed), l broadcast via LDS.
// grid (16 qt, 64 bh), x-fastest: consecutive blocks share K/V of one bh.
// LDS 48.5 KB -> 3 blocks/CU.
// ---------------------------------------------------------------------------
__global__ __launch_bounds__(256, 3) void attn_kernel(
    const ushort* __restrict__ Qw, const ushort* __restrict__ Kw,
    const ushort* __restrict__ Vtw, ushort* __restrict__ attn)
{
    __shared__ ushort Ks[2 * 4096];
    __shared__ ushort Vts[2 * 4096];
    __shared__ ushort Ps[128 * 64];
    __shared__ float red[128];

    const int tid = threadIdx.x;
    const int w = tid >> 6, lane = tid & 63;
    const int ln = tid & 15, quad = (tid >> 4) & 3;
    const int bh = blockIdx.y, b = bh >> 4, h = bh & 15;
    const int qt = blockIdx.x;

    const ushort* Qg = Qw + (size_t)bh * 131072 + (size_t)qt * 8192;
    const ushort* Kg = Kw + (size_t)bh * 131072;
    const ushort* Vg = Vtw + (size_t)bh * 131072;

    // Q fragments (B-operand): lane (ln,quad) holds Q[q=w*32+qs*16+ln][d-chunk]
    short8 bq[2][2];
#pragma unroll
    for (int qs = 0; qs < 2; ++qs)
#pragma unroll
        for (int ks = 0; ks < 2; ++ks)
            bq[qs][ks] = *(const short8*)&Qg[(w * 32 + qs * 16 + ln) * 64 + ks * 32 + quad * 8];

    int offK[2], offV[2], lseg[2];
#pragma unroll
    for (int rr = 0; rr < 2; ++rr) {
        int idx = (rr * 4 + w) * 64 + lane;
        int r = idx >> 3, cst = idx & 7, csrc = cst ^ (r & 7);
        offK[rr] = r * 64 + csrc * 8;
        offV[rr] = r * 2048 + csrc * 8;
        lseg[rr] = (rr * 4 + w) * 512;
    }

    // prologue: stage kt=0 into buffer 0
#pragma unroll
    for (int rr = 0; rr < 2; ++rr) gll16(&Kg[offK[rr]], &Ks[lseg[rr]]);
#pragma unroll
    for (int rr = 0; rr < 2; ++rr) gll16(&Vg[offV[rr]], &Vts[lseg[rr]]);

    f32x4 Of[2][4] = {};
    float psum[2] = {0.f, 0.f};

    for (int kt = 0; kt < 32; ++kt) {
        __syncthreads();               // drains own vmcnt -> buf[cur] complete
        const int cur = (kt & 1) * 4096;
        if (kt < 31) {
            const int nx = 4096 - cur; // prefetch kt+1 during compute of kt
#pragma unroll
            for (int rr = 0; rr < 2; ++rr)
                gll16(&Kg[(kt + 1) * 4096 + offK[rr]], &Ks[nx + lseg[rr]]);
#pragma unroll
            for (int rr = 0; rr < 2; ++rr)
                gll16(&Vg[(kt + 1) * 64 + offV[rr]], &Vts[nx + lseg[rr]]);
        }
        const ushort* ksm = &Ks[cur];
        const ushort* vsm = &Vts[cur];

        // S^T = K · Q^T : 64 kv x 32 q per wave
        f32x4 sa[4][2];
#pragma unroll
        for (int kv = 0; kv < 4; ++kv) {
            short8 a0 = *(const short8*)&ksm[(kv * 16 + ln) * 64 + (quad ^ (ln & 7)) * 8];
            short8 a1 = *(const short8*)&ksm[(kv * 16 + ln) * 64 + ((4 + quad) ^ (ln & 7)) * 8];
#pragma unroll
            for (int qs = 0; qs < 2; ++qs) {
                f32x4 s = {};
                s = MFMA16(a0, bq[qs][0], s);
                s = MFMA16(a1, bq[qs][1], s);
                sa[kv][qs] = s;
            }
        }

        // p = exp2(s); accumulate l per-lane; packed P into [q][kv] LDS
#pragma unroll
        for (int qs = 0; qs < 2; ++qs) {
            int qrow = w * 32 + qs * 16 + ln;
#pragma unroll
            for (int kv = 0; kv < 4; ++kv) {
                float p0 = __builtin_amdgcn_exp2f(sa[kv][qs][0]);
                float p1 = __builtin_amdgcn_exp2f(sa[kv][qs][1]);
                float p2 = __builtin_amdgcn_exp2f(sa[kv][qs][2]);
                float p3 = __builtin_amdgcn_exp2f(sa[kv][qs][3]);
                psum[qs] += (p0 + p1) + (p2 + p3);
                uint2 pk2;
                pk2.x = pk_bf16(p0, p1);
                pk2.y = pk_bf16(p2, p3);
                int c = 2 * kv + (quad >> 1);
                *(uint2*)&Ps[qrow * 64 + ((c ^ (ln & 7)) * 8) + (quad & 1) * 4] = pk2;
            }
        }

        // O += P · V (P rows are wave-private: no barrier needed)
#pragma unroll
        for (int ks = 0; ks < 2; ++ks) {
            short8 vb[4], pa[2];
#pragma unroll
            for (int ds = 0; ds < 4; ++ds)
                vb[ds] = *(const short8*)&vsm[(ds * 16 + ln) * 64 +
                                              ((ks * 4 + quad) ^ (ln & 7)) * 8];
#pragma unroll
            for (int qs = 0; qs < 2; ++qs)
                pa[qs] = *(const short8*)&Ps[(w * 32 + qs * 16 + ln) * 64 +
                                             ((ks * 4 + quad) ^ (ln & 7)) * 8];
#pragma unroll
            for (int qs = 0; qs < 2; ++qs)
#pragma unroll
                for (int ds = 0; ds < 4; ++ds)
                    Of[qs][ds] = MFMA16(pa[qs], vb[ds], Of[qs][ds]);
        }
    }

    // l reduce + broadcast 1/l through LDS (O rows are (quad,reg)-mapped q)
#pragma unroll
    for (int qs = 0; qs < 2; ++qs) {
        float l = psum[qs];
        l += __shfl_xor(l, 16);
        l += __shfl_xor(l, 32);
        if (quad == 0) red[w * 32 + qs * 16 + ln] = __builtin_amdgcn_rcpf(l);
    }
    __syncthreads();

#pragma unroll
    for (int qs = 0; qs < 2; ++qs) {
        f32x4 inv = *(const f32x4*)&red[w * 32 + qs * 16 + quad * 4];
#pragma unroll
        for (int ds = 0; ds < 4; ++ds) {
#pragma unroll
            for (int r = 0; r < 4; ++r) {
                int t = qt * 128 + w * 32 + qs * 16 + quad * 4 + r;
                int col = h * 64 + ds * 16 + ln;
                attn[((size_t)(b * 2048 + t) << 10) + col] =
                    (ushort)f2b(Of[qs][ds][r] * inv[r]);
            }
        }
    }
}

// ---------------------------------------------------------------------------
extern "C" void kernel_launch(void* const* d_in, const int* in_sizes, int n_in,
                              void* d_out, int out_size, void* d_ws, size_t ws_size,
                              hipStream_t stream)
{
    const float* query   = (const float*)d_in[0];
    const float* context = (const float*)d_in[1];
    const float* Wq = (const float*)d_in[2];
    const float* bq = (const float*)d_in[3];
    const float* Wk = (const float*)d_in[4];
    const float* bk = (const float*)d_in[5];
    const float* Wv = (const float*)d_in[6];
    const float* bv = (const float*)d_in[7];
    const float* Wo = (const float*)d_in[8];
    const float* bo = (const float*)d_in[9];

    char* ws = (char*)d_ws;
    ushort* WT  = (ushort*)ws;                        // 4 x 2 MB bf16 [n][k]
    ushort* Qb  = (ushort*)(ws + 8388608);            // query bf16; later Aw
    ushort* Qw  = (ushort*)(ws + 25165824);           // [b,h,t,d] (pre-scaled)
    ushort* Kw  = (ushort*)(ws + 41943040);           // [b,h,t,d]
    ushort* Vtw = (ushort*)(ws + 58720256);           // [b,h,d,t]
    ushort* Aw  = Qb;                                 // attn out reuses Qb
    ushort* Cb  = (ushort*)d_out;                     // context bf16 in d_out

    const float SCALE = 0.18033688011112042f;         // log2(e)/sqrt(64)

    in_cvt_kernel<<<dim3(4096, 2), 256, 0, stream>>>(query, context, Qb, Cb);
    wt_cvt_kernel<<<dim3(16, 16, 4), 256, 0, stream>>>(Wq, Wk, Wv, Wo, WT);
    gemm_kernel<0><<<dim3(8, 64), 256, 0, stream>>>(Qb, WT + 0 * 1048576, bq, Qw, SCALE);
    kv_kernel<<<dim3(16, 64), 256, 0, stream>>>(Cb, WT + 1 * 1048576,
                                                WT + 2 * 1048576, bk, bv, Kw, Vtw);
    attn_kernel<<<dim3(16, 64), 256, 0, stream>>>(Qw, Kw, Vtw, Aw);
    gemm_kernel<3><<<dim3(8, 64), 256, 0, stream>>>(Aw, WT + 3 * 1048576, bo,
                                                    (float*)d_out, 1.0f);
}

// Round 7
// 326.068 us; speedup vs baseline: 2.2234x; 1.0098x over previous
//
#include <hip/hip_runtime.h>
#include <hip/hip_bf16.h>
#include <cstdint>

typedef __attribute__((ext_vector_type(8))) short short8;
typedef __attribute__((ext_vector_type(4))) short short4_t;
typedef __attribute__((ext_vector_type(4))) float f32x4;

#define MFMA16(a, b, c) __builtin_amdgcn_mfma_f32_16x16x32_bf16(a, b, c, 0, 0, 0)
// v_mfma_f32_16x16x16_bf16 (4-pass, V4s x V4s -> V4f). NOTE: do NOT guard
// with __has_builtin — it returns false on the host pass (aux-target
// builtins are callable but not "visible"), which is what broke R6.
#define MFMA16K16(a, b, c) __builtin_amdgcn_mfma_f32_16x16x16bf16_1k(a, b, c, 0, 0, 0)

__device__ __forceinline__ short f2b(float f) {
    union { float fp; unsigned u; } un; un.fp = f;
    unsigned r = un.u + 0x7fffu + ((un.u >> 16) & 1u);
    return (short)(r >> 16);
}

#if __has_builtin(__builtin_amdgcn_cvt_pk_bf16_f32)
__device__ __forceinline__ unsigned pk_bf16(float a, float b) {
    auto r = __builtin_amdgcn_cvt_pk_bf16_f32(a, b);
    unsigned u; __builtin_memcpy(&u, &r, 4); return u;
}
#else
__device__ __forceinline__ unsigned pk_bf16(float a, float b) {
    return (unsigned)(unsigned short)f2b(a) | ((unsigned)(unsigned short)f2b(b) << 16);
}
#endif

union pk4_u { unsigned u2[2]; short4_t s; };

typedef const __attribute__((address_space(1))) unsigned g_as1;
typedef __attribute__((address_space(3))) unsigned l_as3;
__device__ __forceinline__ void gll16(const ushort* g, ushort* l) {
    __builtin_amdgcn_global_load_lds((g_as1*)g, (l_as3*)l, 16, 0, 0);
}

// ---------------------------------------------------------------------------
// fp32 -> bf16 convert of query / context
// ---------------------------------------------------------------------------
__global__ __launch_bounds__(256) void in_cvt_kernel(
    const float* __restrict__ q, const float* __restrict__ c,
    ushort* __restrict__ qb, ushort* __restrict__ cb)
{
    const float* src = blockIdx.y ? c : q;
    ushort* dst = blockIdx.y ? cb : qb;
    size_t i = ((size_t)blockIdx.x * 256 + threadIdx.x) * 8;
    float4 v0 = *(const float4*)&src[i];
    float4 v1 = *(const float4*)&src[i + 4];
    uint4 o;
    o.x = pk_bf16(v0.x, v0.y); o.y = pk_bf16(v0.z, v0.w);
    o.z = pk_bf16(v1.x, v1.y); o.w = pk_bf16(v1.z, v1.w);
    *(uint4*)&dst[i] = o;
}

// ---------------------------------------------------------------------------
// Weight transpose+convert: fp32 [k][n] -> bf16 [n][k]
// ---------------------------------------------------------------------------
__global__ __launch_bounds__(256) void wt_cvt_kernel(
    const float* __restrict__ Wq, const float* __restrict__ Wk,
    const float* __restrict__ Wv, const float* __restrict__ Wo,
    ushort* __restrict__ wt)
{
    __shared__ float Ts[64 * 65];
    const int z = blockIdx.z;
    const float* W = (z == 0) ? Wq : (z == 1) ? Wk : (z == 2) ? Wv : Wo;
    ushort* WT = wt + (size_t)z * (1024 * 1024);
    const int n0 = blockIdx.x * 64, k0 = blockIdx.y * 64;
    const int tid = threadIdx.x;

#pragma unroll
    for (int rr = 0; rr < 4; ++rr) {
        int u = tid + rr * 256;
        int r = u >> 4, c = (u & 15) * 4;
        float4 v = *(const float4*)&W[(size_t)(k0 + r) * 1024 + n0 + c];
        Ts[r * 65 + c + 0] = v.x; Ts[r * 65 + c + 1] = v.y;
        Ts[r * 65 + c + 2] = v.z; Ts[r * 65 + c + 3] = v.w;
    }
    __syncthreads();
#pragma unroll
    for (int rr = 0; rr < 4; ++rr) {
        int u = tid + rr * 256;
        int rn = u >> 4, ck = (u & 15) * 4;
        short4_t o;
        o[0] = f2b(Ts[(ck + 0) * 65 + rn]);
        o[1] = f2b(Ts[(ck + 1) * 65 + rn]);
        o[2] = f2b(Ts[(ck + 2) * 65 + rn]);
        o[3] = f2b(Ts[(ck + 3) * 65 + rn]);
        *(short4_t*)&WT[(size_t)(n0 + rn) * 1024 + k0 + ck] = o;
    }
}

// ---------------------------------------------------------------------------
// GEMM (R2-proven): grid (8 n-tiles, 64 m-tiles), x-fastest.
// MODE 0: out bf16 [b,h,t,d] scaled  (Q projection)
// MODE 3: out fp32 row-major [m][n]  (output projection)
// ---------------------------------------------------------------------------
template <int MODE>
__global__ __launch_bounds__(256) void gemm_kernel(
    const ushort* __restrict__ Ag, const ushort* __restrict__ BT,
    const float* __restrict__ bias, void* __restrict__ Outp, float scale)
{
    __shared__ ushort As[128 * 64];
    __shared__ ushort Bs[128 * 64];
    const int tid = threadIdx.x;
    const int w = tid >> 6, lane = tid & 63;
    const int ln = tid & 15, quad = (tid >> 4) & 3;
    const int wm = w >> 1, wn = w & 1;
    const int m0 = blockIdx.y * 128, n0 = blockIdx.x * 128;

    int offA[4], offB[4], lseg[4];
#pragma unroll
    for (int rr = 0; rr < 4; ++rr) {
        int idx = (rr * 4 + w) * 64 + lane;
        int r = idx >> 3, cst = idx & 7, csrc = cst ^ (r & 7);
        offA[rr] = (m0 + r) * 1024 + csrc * 8;
        offB[rr] = (n0 + r) * 1024 + csrc * 8;
        lseg[rr] = (rr * 4 + w) * 512;
    }

    f32x4 acc[4][4] = {};

    for (int kk = 0; kk < 1024; kk += 64) {
        __syncthreads();
#pragma unroll
        for (int rr = 0; rr < 4; ++rr)
            gll16(&Ag[(size_t)(offA[rr] + kk)], &As[lseg[rr]]);
#pragma unroll
        for (int rr = 0; rr < 4; ++rr)
            gll16(&BT[(size_t)(offB[rr] + kk)], &Bs[lseg[rr]]);
        __syncthreads();

#pragma unroll
        for (int ks = 0; ks < 2; ++ks) {
            short8 af[4], bfr[4];
#pragma unroll
            for (int i = 0; i < 4; ++i)
                af[i] = *(const short8*)&As[(wm * 64 + i * 16 + ln) * 64 +
                                            ((ks * 4 + quad) ^ (ln & 7)) * 8];
#pragma unroll
            for (int j = 0; j < 4; ++j)
                bfr[j] = *(const short8*)&Bs[(wn * 64 + j * 16 + ln) * 64 +
                                             ((ks * 4 + quad) ^ (ln & 7)) * 8];
#pragma unroll
            for (int i = 0; i < 4; ++i)
#pragma unroll
                for (int j = 0; j < 4; ++j)
                    acc[i][j] = MFMA16(af[i], bfr[j], acc[i][j]);
        }
    }

#pragma unroll
    for (int j = 0; j < 4; ++j) {
        int n = n0 + wn * 64 + j * 16 + ln;
        float bv = bias[n];
#pragma unroll
        for (int i = 0; i < 4; ++i) {
            int mb = m0 + wm * 64 + i * 16 + quad * 4;
            if (MODE == 3) {
                float* Out = (float*)Outp;
#pragma unroll
                for (int r = 0; r < 4; ++r)
                    Out[(size_t)(mb + r) * 1024 + n] = acc[i][j][r] + bv;
            } else {
                ushort* Out = (ushort*)Outp;
                int h = n >> 6, d = n & 63;
#pragma unroll
                for (int r = 0; r < 4; ++r) {
                    int m = mb + r, b = m >> 11, t = m & 2047;
                    Out[(((size_t)(b * 16 + h) * 2048 + t) << 6) + d] =
                        (ushort)f2b((acc[i][j][r] + bv) * scale);
                }
            }
        }
    }
}

// ---------------------------------------------------------------------------
// Fused K+V projection (unchanged from R5). grid (16, 64), x-fastest.
// ---------------------------------------------------------------------------
__global__ __launch_bounds__(256) void kv_kernel(
    const ushort* __restrict__ Cb, const ushort* __restrict__ WTk,
    const ushort* __restrict__ WTv,
    const float* __restrict__ bk, const float* __restrict__ bv,
    ushort* __restrict__ Kw, ushort* __restrict__ Vtw)
{
    __shared__ ushort As[128 * 64];
    __shared__ ushort Bs[128 * 64];
    const int tid = threadIdx.x;
    const int w = tid >> 6, lane = tid & 63;
    const int ln = tid & 15, quad = (tid >> 4) & 3;
    const int wm = w >> 1, wn = w & 1;
    const int z = blockIdx.x >> 3;
    const int n0 = (blockIdx.x & 7) * 128;
    const int m0 = blockIdx.y * 128;
    const ushort* BT = z ? WTv : WTk;

    int offA[4], offB[4], lseg[4];
#pragma unroll
    for (int rr = 0; rr < 4; ++rr) {
        int idx = (rr * 4 + w) * 64 + lane;
        int r = idx >> 3, cst = idx & 7, csrc = cst ^ (r & 7);
        offA[rr] = (m0 + r) * 1024 + csrc * 8;
        offB[rr] = (n0 + r) * 1024 + csrc * 8;
        lseg[rr] = (rr * 4 + w) * 512;
    }

    f32x4 acc[4][4] = {};

    for (int kk = 0; kk < 1024; kk += 64) {
        __syncthreads();
#pragma unroll
        for (int rr = 0; rr < 4; ++rr)
            gll16(&Cb[(size_t)(offA[rr] + kk)], &As[lseg[rr]]);
#pragma unroll
        for (int rr = 0; rr < 4; ++rr)
            gll16(&BT[(size_t)(offB[rr] + kk)], &Bs[lseg[rr]]);
        __syncthreads();

#pragma unroll
        for (int ks = 0; ks < 2; ++ks) {
            short8 af[4], bfr[4];
#pragma unroll
            for (int i = 0; i < 4; ++i)
                af[i] = *(const short8*)&As[(wm * 64 + i * 16 + ln) * 64 +
                                            ((ks * 4 + quad) ^ (ln & 7)) * 8];
#pragma unroll
            for (int j = 0; j < 4; ++j)
                bfr[j] = *(const short8*)&Bs[(wn * 64 + j * 16 + ln) * 64 +
                                             ((ks * 4 + quad) ^ (ln & 7)) * 8];
#pragma unroll
            for (int i = 0; i < 4; ++i)
#pragma unroll
                for (int j = 0; j < 4; ++j)
                    acc[i][j] = MFMA16(af[i], bfr[j], acc[i][j]);
        }
    }

#pragma unroll
    for (int j = 0; j < 4; ++j) {
        int n = n0 + wn * 64 + j * 16 + ln;
        int h = n >> 6, d = n & 63;
        if (z == 0) {
            float bvv = bk[n];
#pragma unroll
            for (int i = 0; i < 4; ++i) {
                int mb = m0 + wm * 64 + i * 16 + quad * 4;
#pragma unroll
                for (int r = 0; r < 4; ++r) {
                    int m = mb + r, b = m >> 11, t = m & 2047;
                    Kw[(((size_t)(b * 16 + h) * 2048 + t) << 6) + d] =
                        (ushort)f2b(acc[i][j][r] + bvv);
                }
            }
        } else {
            float bvv = bv[n];
#pragma unroll
            for (int i = 0; i < 4; ++i) {
                int mb = m0 + wm * 64 + i * 16 + quad * 4;
                int b = mb >> 11, t = mb & 2047;
                short4_t o;
                o[0] = f2b(acc[i][j][0] + bvv); o[1] = f2b(acc[i][j][1] + bvv);
                o[2] = f2b(acc[i][j][2] + bvv); o[3] = f2b(acc[i][j][3] + bvv);
                *(short4_t*)&Vtw[(((size_t)((b * 16 + h) * 64 + d)) << 11) + t] = o;
            }
        }
    }
}

// ---------------------------------------------------------------------------
// Flash attention v3: P never touches LDS.
// S^T = K·Q^T comes out of the K=32 MFMA in C-layout (col=q=ln, rows=quad*4+r)
// which is EXACTLY the A/B-operand layout of v_mfma_f32_16x16x16_bf16
// (k = quad*4 + j). So exp2+pack produces PV's B-operand fragments directly
// in-register. The softmax denominator is an extra K=16 MFMA with A=ones
// (every output row = column-sum of P), landing in the same lane (col=q=ln)
// as O — no shuffles, no LDS broadcast.
// LDS: K tile 8KB + V^T tile 8KB, single-buffered. Fixed-max softmax
// (Q pre-scaled by log2e/8). grid (16 qt, 64 bh), x-fastest.
// ---------------------------------------------------------------------------
__global__ __launch_bounds__(256, 4) void attn_kernel(
    const ushort* __restrict__ Qw, const ushort* __restrict__ Kw,
    const ushort* __restrict__ Vtw, ushort* __restrict__ attn)
{
    __shared__ ushort Ks[4096];      // 64 kv x 64 d, XOR chunk swizzle
    __shared__ ushort Vts[4096];     // 64 d  x 64 kv, XOR chunk swizzle

    const int tid = threadIdx.x;
    const int w = tid >> 6, lane = tid & 63;
    const int ln = tid & 15, quad = (tid >> 4) & 3;
    const int bh = blockIdx.y, b = bh >> 4, h = bh & 15;
    const int qt = blockIdx.x;

    const ushort* Qg = Qw + (size_t)bh * 131072 + (size_t)qt * 8192;
    const ushort* Kg = Kw + (size_t)bh * 131072;
    const ushort* Vg = Vtw + (size_t)bh * 131072;

    // Q fragments (B-operand of K=32 QK): lane holds Q[q=w*32+qs*16+ln][d-chunk]
    short8 bq[2][2];
#pragma unroll
    for (int qs = 0; qs < 2; ++qs)
#pragma unroll
        for (int ks = 0; ks < 2; ++ks)
            bq[qs][ks] = *(const short8*)&Qg[(w * 32 + qs * 16 + ln) * 64 + ks * 32 + quad * 8];

    int offK[2], offV[2], lseg[2];
#pragma unroll
    for (int rr = 0; rr < 2; ++rr) {
        int idx = (rr * 4 + w) * 64 + lane;
        int r = idx >> 3, cst = idx & 7, csrc = cst ^ (r & 7);
        offK[rr] = r * 64 + csrc * 8;
        offV[rr] = r * 2048 + csrc * 8;
        lseg[rr] = (rr * 4 + w) * 512;
    }

    const short4_t ones = {(short)0x3F80, (short)0x3F80, (short)0x3F80, (short)0x3F80};

    f32x4 Of[2][4] = {};     // O^T: col = q = ln (qs slab), rows = d-local quad*4+r
    f32x4 lac[2] = {};       // col-sums of P: col = q = ln, rows all equal

    for (int kt = 0; kt < 32; ++kt) {
        __syncthreads();
#pragma unroll
        for (int rr = 0; rr < 2; ++rr)
            gll16(&Kg[kt * 4096 + offK[rr]], &Ks[lseg[rr]]);
#pragma unroll
        for (int rr = 0; rr < 2; ++rr)
            gll16(&Vg[kt * 64 + offV[rr]], &Vts[lseg[rr]]);
        __syncthreads();

        // S^T = K · Q^T : 64 kv x 32 q per wave (K=32 MFMA)
        f32x4 sa[4][2];
#pragma unroll
        for (int kv = 0; kv < 4; ++kv) {
            short8 a0 = *(const short8*)&Ks[(kv * 16 + ln) * 64 + (quad ^ (ln & 7)) * 8];
            short8 a1 = *(const short8*)&Ks[(kv * 16 + ln) * 64 + ((4 + quad) ^ (ln & 7)) * 8];
#pragma unroll
            for (int qs = 0; qs < 2; ++qs) {
                f32x4 s = {};
                s = MFMA16(a0, bq[qs][0], s);
                s = MFMA16(a1, bq[qs][1], s);
                sa[kv][qs] = s;
            }
        }

        // exp2 + pack: pf[kv][qs] IS the B-operand of the K=16 PV MFMA
        short4_t pf[4][2];
#pragma unroll
        for (int qs = 0; qs < 2; ++qs)
#pragma unroll
            for (int kv = 0; kv < 4; ++kv) {
                float p0 = __builtin_amdgcn_exp2f(sa[kv][qs][0]);
                float p1 = __builtin_amdgcn_exp2f(sa[kv][qs][1]);
                float p2 = __builtin_amdgcn_exp2f(sa[kv][qs][2]);
                float p3 = __builtin_amdgcn_exp2f(sa[kv][qs][3]);
                pk4_u pu;
                pu.u2[0] = pk_bf16(p0, p1);
                pu.u2[1] = pk_bf16(p2, p3);
                pf[kv][qs] = pu.s;
                lac[qs] = MFMA16K16(ones, pu.s, lac[qs]);   // denominator
            }

        // O^T += V^T · P : 4 kv-blocks x 4 d-blocks x 2 q-slabs, K=16
#pragma unroll
        for (int kv = 0; kv < 4; ++kv) {
#pragma unroll
            for (int ds = 0; ds < 4; ++ds) {
                short4_t vf = *(const short4_t*)&Vts[(ds * 16 + ln) * 64 +
                    (((2 * kv + (quad >> 1)) ^ (ln & 7)) * 8) + (quad & 1) * 4];
#pragma unroll
                for (int qs = 0; qs < 2; ++qs)
                    Of[qs][ds] = MFMA16K16(vf, pf[kv][qs], Of[qs][ds]);
            }
        }
    }

    // finalize: lane ln owns q = w*32 + qs*16 + ln for both l and O columns
#pragma unroll
    for (int qs = 0; qs < 2; ++qs) {
        float inv = __builtin_amdgcn_rcpf(lac[qs][0]);
        int t = qt * 128 + w * 32 + qs * 16 + ln;
        size_t base = ((size_t)(b * 2048 + t) << 10) + h * 64;
#pragma unroll
        for (int ds = 0; ds < 4; ++ds) {
            uint2 o;
            o.x = pk_bf16(Of[qs][ds][0] * inv, Of[qs][ds][1] * inv);
            o.y = pk_bf16(Of[qs][ds][2] * inv, Of[qs][ds][3] * inv);
            *(uint2*)&attn[base + ds * 16 + quad * 4] = o;
        }
    }
}

// ---------------------------------------------------------------------------
extern "C" void kernel_launch(void* const* d_in, const int* in_sizes, int n_in,
                              void* d_out, int out_size, void* d_ws, size_t ws_size,
                              hipStream_t stream)
{
    const float* query   = (const float*)d_in[0];
    const float* context = (const float*)d_in[1];
    const float* Wq = (const float*)d_in[2];
    const float* bq = (const float*)d_in[3];
    const float* Wk = (const float*)d_in[4];
    const float* bk = (const float*)d_in[5];
    const float* Wv = (const float*)d_in[6];
    const float* bv = (const float*)d_in[7];
    const float* Wo = (const float*)d_in[8];
    const float* bo = (const float*)d_in[9];

    char* ws = (char*)d_ws;
    ushort* WT  = (ushort*)ws;                        // 4 x 2 MB bf16 [n][k]
    ushort* Qb  = (ushort*)(ws + 8388608);            // query bf16; later Aw
    ushort* Qw  = (ushort*)(ws + 25165824);           // [b,h,t,d] (pre-scaled)
    ushort* Kw  = (ushort*)(ws + 41943040);           // [b,h,t,d]
    ushort* Vtw = (ushort*)(ws + 58720256);           // [b,h,d,t]
    ushort* Aw  = Qb;                                 // attn out reuses Qb
    ushort* Cb  = (ushort*)d_out;                     // context bf16 in d_out

    const float SCALE = 0.18033688011112042f;         // log2(e)/sqrt(64)

    in_cvt_kernel<<<dim3(4096, 2), 256, 0, stream>>>(query, context, Qb, Cb);
    wt_cvt_kernel<<<dim3(16, 16, 4), 256, 0, stream>>>(Wq, Wk, Wv, Wo, WT);
    gemm_kernel<0><<<dim3(8, 64), 256, 0, stream>>>(Qb, WT + 0 * 1048576, bq, Qw, SCALE);
    kv_kernel<<<dim3(16, 64), 256, 0, stream>>>(Cb, WT + 1 * 1048576,
                                                WT + 2 * 1048576, bk, bv, Kw, Vtw);
    attn_kernel<<<dim3(16, 64), 256, 0, stream>>>(Qw, Kw, Vtw, Aw);
    gemm_kernel<3><<<dim3(8, 64), 256, 0, stream>>>(Aw, WT + 3 * 1048576, bo,
                                                    (float*)d_out, 1.0f);
}